// Round 5
// baseline (257.235 us; speedup 1.0000x reference)
//
#include <hip/hip_runtime.h>
#include <hip/hip_bf16.h>

// Problem constants
#define BB 4
#define SS 4096
#define DM 1024
#define HH 16
#define PP 32
#define RR 8
#define DD 64
#define NTOK (BB*SS)          // 16384 tokens
#define MM NTOK               // GEMM M
#define NN DM                 // GEMM N
#define KK DM                 // GEMM K

typedef __attribute__((ext_vector_type(8))) short short8;
typedef __attribute__((ext_vector_type(4))) float floatx4;

static __device__ inline short f2bf(float f) {
    union { __hip_bfloat16 b; short s; } u; u.b = __float2bfloat16(f); return u.s;
}
static __device__ inline short8 pack8(float4 lo, float4 hi) {
    short8 r;
    r[0] = f2bf(lo.x); r[1] = f2bf(lo.y); r[2] = f2bf(lo.z); r[3] = f2bf(lo.w);
    r[4] = f2bf(hi.x); r[5] = f2bf(hi.y); r[6] = f2bf(hi.z); r[7] = f2bf(hi.w);
    return r;
}

// Fast RNE bf16 pack: identical bits to __float2bfloat16 for finite inputs.
static __device__ inline unsigned bfr(float f) {
    unsigned u = __float_as_uint(f);
    return u + 0x7fffu + ((u >> 16) & 1u);
}
static __device__ inline int pk2(float a, float b) {  // low16=bf(a), high16=bf(b)
    return __builtin_amdgcn_perm(bfr(b), bfr(a), 0x07060302);
}
static __device__ inline short8 pk8(float4 lo, float4 hi) {
    union { short8 s; int i[4]; } r;
    r.i[0] = pk2(lo.x, lo.y); r.i[1] = pk2(lo.z, lo.w);
    r.i[2] = pk2(hi.x, hi.y); r.i[3] = pk2(hi.z, hi.w);
    return r.s;
}

// ---------------------------------------------------------------------------
// Kernel 1: W_out (f32 [k][n]) -> bf16 MFMA B-fragment order (unchanged).
// ---------------------------------------------------------------------------
__global__ __launch_bounds__(256) void convert_w(const float* __restrict__ Wo,
                                                 __hip_bfloat16* __restrict__ wsw) {
    int tid = blockIdx.x * 256 + threadIdx.x;     // 0 .. 131071
    int l = tid & 63;
    int kblk = (tid >> 6) & 31;
    int ntile = tid >> 11;
    int col = ntile * 16 + (l & 15);
    int krow = kblk * 32 + (l >> 4) * 8;
#pragma unroll
    for (int j = 0; j < 8; ++j) {
        wsw[(size_t)tid * 8 + j] = __float2bfloat16(Wo[(size_t)(krow + j) * NN + col]);
    }
}

// ---------------------------------------------------------------------------
// Kernel 1b: K_state / V_state -> MFMA A-frag layouts (unchanged).
// ---------------------------------------------------------------------------
__global__ __launch_bounds__(256) void convert_kv(const float* __restrict__ Kst,
                                                  const float* __restrict__ Vst,
                                                  __hip_bfloat16* __restrict__ kfrag,
                                                  __hip_bfloat16* __restrict__ vfrag) {
    int tid = blockIdx.x * 256 + threadIdx.x;     // 0..65535
    int arr = tid >> 15;
    int idx = tid & 32767;
    int h = idx >> 11, blk = (idx >> 6) & 31, fl = idx & 63;
    int fm = fl & 15, fk = fl >> 4;
    short8 val;
    short* dst;
    if (arr == 0) {
        int mt = blk >> 1, kb = blk & 1;
        int pr = mt * 16 + fm, d0 = kb * 32 + fk * 8;
        const float* src = Kst + ((size_t)h * 256 + pr) * 64 + d0;
        float4 lo = *(const float4*)src, hi = *(const float4*)(src + 4);
        val = pack8(lo, hi);
        dst = (short*)kfrag + (size_t)idx * 8;
    } else {
        int mt = blk >> 3, kb = blk & 7;
        int d = mt * 16 + fm, pr0 = kb * 32 + fk * 8;
        const float* src = Vst + ((size_t)h * 256 + pr0) * 64 + d;
#pragma unroll
        for (int j = 0; j < 8; ++j) val[j] = f2bf(src[j * 64]);
        dst = (short*)vfrag + (size_t)idx * 8;
    }
    *(short8*)dst = val;
}

// ---------------------------------------------------------------------------
// Kernel 2 (v8b): fused router + dense-MFMA SSE attention, 8-wave blocks.
// v8 -> v8b: BUGFIX — v8's staging wrote only 1 float4 per thread (3/4 of
// the xs tile left as garbage -> absmax 0.142). Now all 512 threads copy
// 8 floats each (full 64x64 tile). Also: scores GEMM split per kb (load 4+2
// frags, 8 MFMAs, repeat) to cut peak live regs ~127 -> ~108 under the
// (512,4) 128-reg cap (round-1 spill lesson). MFMA accumulate order and all
// operand bits identical to v7. Scores phase sits before barrier [A]
// (reads global only — legal between staging writes and logits reads).
// ---------------------------------------------------------------------------
__global__ __launch_bounds__(512, 4) void attn_v8b(const float* __restrict__ x,
                                                   const float* __restrict__ Wr,
                                                   const __hip_bfloat16* __restrict__ kfrag,
                                                   const __hip_bfloat16* __restrict__ vfrag,
                                                   const int* __restrict__ kp,
                                                   __hip_bfloat16* __restrict__ hb) {
    // Aliased LDS region (40960 B total):
    //   [0,32768):  wf (heads-phase B-frags)  -- written after top-k sync
    //   [0,17408):  xs[64][68]                -- dead after logits phase
    //   [17408,26624): Lg[64][36]             -- dead after top-k phase
    //   [32768,40960): gatesT[32][64]         -- live during wf phase (disjoint)
    __shared__ __align__(16) char smem[40960];
    float (*xs)[68]     = (float (*)[68])smem;
    float (*Lg)[36]     = (float (*)[36])(smem + 17408);
    short* wf           = (short*)smem;
    float (*gatesT)[64] = (float (*)[64])(smem + 32768);

    const int tid = threadIdx.x;
    const int lane = tid & 63;
    const int w = tid >> 6;                        // 0..7
    const int l15 = lane & 15, l4 = lane >> 4;
    const int t0 = blockIdx.x * 64;
    const int h = blockIdx.y;

    // ---- stage x tile [64 t x 64 d] into LDS: 512 threads x 8 floats ----
    {
        int row = tid >> 3, q = tid & 7;
        const float4* src = (const float4*)(x + (size_t)(t0 + row) * DM + h * 64 + q * 8);
        float4 v0 = src[0], v1 = src[1];
        float4* dst = (float4*)&xs[row][q * 8];
        dst[0] = v0; dst[1] = v1;
    }

    // ---- preload router weights (exact R1 pattern, all waves) ----
    const int p = lane & 31, dh = lane >> 5;
    float wreg[32];
    {
        const float* wrp = Wr + (size_t)h * (DD * PP) + dh * 32 * PP + p;
#pragma unroll
        for (int dd = 0; dd < 32; ++dd) wreg[dd] = wrp[dd * PP];
    }
    const int kkv = kp[0];

    // ---- scores GEMM: S^T[pr][t]; wave owns 2 m-tiles x 4 n-tiles.
    //      Global reads only -> placed before barrier [A]. Per-kb split to
    //      bound register liveness; accumulate order identical to v7. ----
    floatx4 acc[2][4] = {};
#pragma unroll
    for (int kb = 0; kb < 2; ++kb) {
        short8 xbk[4];
#pragma unroll
        for (int nt = 0; nt < 4; ++nt) {
            const float* bp = x + (size_t)(t0 + nt * 16 + l15) * DM + h * 64 + kb * 32 + l4 * 8;
            float4 lo = *(const float4*)bp;
            float4 hi = *(const float4*)(bp + 4);
            xbk[nt] = pk8(lo, hi);
        }
        short8 kak[2];
#pragma unroll
        for (int mi = 0; mi < 2; ++mi)
            kak[mi] = *(const short8*)((const short*)kfrag +
                       ((size_t)(h * 32 + (w * 2 + mi) * 2 + kb) * 512 + lane * 8));
#pragma unroll
        for (int mi = 0; mi < 2; ++mi)
#pragma unroll
            for (int nt = 0; nt < 4; ++nt)
                acc[mi][nt] = __builtin_amdgcn_mfma_f32_16x16x32_bf16(kak[mi], xbk[nt], acc[mi][nt], 0, 0, 0);
    }

    __syncthreads();   // [A] xs staged

    // ---- logits: 8 tokens/wave; per-token chain order IDENTICAL to R1..R7;
    //      even/odd pairs interleaved for ILP (same pairing as v7) ----
    for (int it = 0; it < 8; it += 2) {
        const int ta = w * 8 + it;
        const int tb = ta + 1;
        float la = 0.f, lb = 0.f;
#pragma unroll
        for (int j = 0; j < 8; ++j) {
            float4 qa = *(const float4*)&xs[ta][dh * 32 + 4 * j];
            float4 qb = *(const float4*)&xs[tb][dh * 32 + 4 * j];
            la += qa.x * wreg[4 * j];     lb += qb.x * wreg[4 * j];
            la += qa.y * wreg[4 * j + 1]; lb += qb.y * wreg[4 * j + 1];
            la += qa.z * wreg[4 * j + 2]; lb += qb.z * wreg[4 * j + 2];
            la += qa.w * wreg[4 * j + 3]; lb += qb.w * wreg[4 * j + 3];
        }
        la += __shfl_xor(la, 32);
        lb += __shfl_xor(lb, 32);
        if (lane < 32) {
            Lg[ta][lane] = la;
            Lg[tb][lane] = lb;
        }
    }
    __syncthreads();   // [B] Lg complete

    // ---- top-k threshold: lanes 0..7, ladder bit-identical to R1..R7 ----
    float thresh = 0.f, a1 = 0.f;
    if (lane < 8) {
        int t = w * 8 + lane;
        float lgr[32];
        const float4* lrow = (const float4*)&Lg[t][0];
#pragma unroll
        for (int c = 0; c < 8; ++c) {
            float4 q4 = lrow[c];
            lgr[4 * c] = q4.x; lgr[4 * c + 1] = q4.y; lgr[4 * c + 2] = q4.z; lgr[4 * c + 3] = q4.w;
        }
        float aa = -INFINITY, b2 = -INFINITY, c3 = -INFINITY, d4 = -INFINITY;
#pragma unroll
        for (int pp = 0; pp < 32; ++pp) {
            float v = lgr[pp];
            float na = fmaxf(aa, v); v = fminf(aa, v); aa = na;
            float nb = fmaxf(b2, v); v = fminf(b2, v); b2 = nb;
            float nc = fmaxf(c3, v); v = fminf(c3, v); c3 = nc;
            d4 = fmaxf(d4, v);
        }
        thresh = (kkv >= 4) ? d4 : (kkv == 3 ? c3 : (kkv == 2 ? b2 : aa));
        a1 = aa;
    }
    // broadcast token-t threshold/max to the 7 sibling lanes
    thresh = __shfl(thresh, lane & 7);
    a1     = __shfl(a1, lane & 7);

    // ---- gates: all 64 lanes, 4 p-values each. exp/mask values identical
    //      bits to the serial version; only den's add order differs (smooth).
    {
        const int t = w * 8 + (lane & 7);
        const int p4 = (lane >> 3) * 4;
        float4 qa = *(const float4*)&Lg[t][p4];
        float e0 = (qa.x >= thresh) ? __expf(qa.x - a1) : 0.f;
        float e1 = (qa.y >= thresh) ? __expf(qa.y - a1) : 0.f;
        float e2 = (qa.z >= thresh) ? __expf(qa.z - a1) : 0.f;
        float e3 = (qa.w >= thresh) ? __expf(qa.w - a1) : 0.f;
        float part = (e0 + e1) + (e2 + e3);
        part += __shfl_xor(part, 8);
        part += __shfl_xor(part, 16);
        part += __shfl_xor(part, 32);
        float inv = 1.f / part;
        gatesT[p4 + 0][t] = e0 * inv;
        gatesT[p4 + 1][t] = e1 * inv;
        gatesT[p4 + 2][t] = e2 * inv;
        gatesT[p4 + 3][t] = e3 * inv;
    }
    __syncthreads();   // [C] gates complete; xs/Lg now dead

    // ---- r-softmax + gate -> w B-frags in LDS (overwrites dead xs/Lg) ----
#pragma unroll
    for (int mi = 0; mi < 2; ++mi) {
        const int mt = w * 2 + mi;
        const int pidx = mt * 2 + (l4 >> 1);
#pragma unroll
        for (int nt = 0; nt < 4; ++nt) {
            float g = gatesT[pidx][nt * 16 + l15];
            float s0 = acc[mi][nt][0] * 0.125f;
            float s1 = acc[mi][nt][1] * 0.125f;
            float s2 = acc[mi][nt][2] * 0.125f;
            float s3 = acc[mi][nt][3] * 0.125f;
            float mx = fmaxf(fmaxf(s0, s1), fmaxf(s2, s3));
            mx = fmaxf(mx, __shfl_xor(mx, 16));
            float e0 = __expf(s0 - mx), e1 = __expf(s1 - mx);
            float e2 = __expf(s2 - mx), e3 = __expf(s3 - mx);
            float loc = (e0 + e1) + (e2 + e3);
            float se = loc + __shfl_xor(loc, 16);
            float ws = g / se;
            int2 pk;
            pk.x = pk2(e0 * ws, e1 * ws);
            pk.y = pk2(e2 * ws, e3 * ws);
            int off = (((mt & 1) * 2 + (l4 >> 1)) * 16 + l15) * 8 + (l4 & 1) * 4;
            *(int2*)&wf[(nt * 8 + (mt >> 1)) * 512 + off] = pk;
        }
    }
    __syncthreads();   // [D] wf complete

    // ---- heads GEMM: H^T[d][t] = Vfrag(A) @ wf(B).
    //      wave w: d-tile = w&3, n-tiles = (w>>2)*2 .. +1. Same kb order. ----
    const int dt = w & 3;
    const int nt0 = (w >> 2) * 2;
    floatx4 h4[2] = {};
#pragma unroll
    for (int kb = 0; kb < 8; ++kb) {
        short8 va = *(const short8*)((const short*)vfrag +
                      ((size_t)(h * 32 + dt * 8 + kb) * 512 + lane * 8));
#pragma unroll
        for (int j = 0; j < 2; ++j) {
            short8 wb = *(const short8*)&wf[((nt0 + j) * 8 + kb) * 512 + lane * 8];
            h4[j] = __builtin_amdgcn_mfma_f32_16x16x32_bf16(va, wb, h4[j], 0, 0, 0);
        }
    }
#pragma unroll
    for (int j = 0; j < 2; ++j) {
        int t = t0 + (nt0 + j) * 16 + l15;
        int2 pk;
        pk.x = pk2(h4[j][0], h4[j][1]);
        pk.y = pk2(h4[j][2], h4[j][3]);
        *(int2*)((short*)hb + (size_t)t * DM + h * 64 + dt * 16 + l4 * 4) = pk;
    }
}

// ---------------------------------------------------------------------------
// Kernel 3 (v3): 2-phase double-buffered m97-style GEMM (T3 minimum recipe)
// + bijective XCD-stripe swizzle. Unchanged from rounds 1-3.
// ---------------------------------------------------------------------------
__global__ __launch_bounds__(256) void gemm_v3(const __hip_bfloat16* __restrict__ Abf,
                                               const __hip_bfloat16* __restrict__ Bsw,
                                               const float* __restrict__ bias,
                                               float* __restrict__ C) {
    __shared__ __align__(16) short As[2][4096];   // 2 x (128 rows x 32 k) = 16 KB
    const int lane = threadIdx.x & 63;
    const int wave = threadIdx.x >> 6;
    const int wm = wave >> 1, wn = wave & 1;

    // Bijective XCD-aware remap. Dispatch index = y*8 + x (x fastest),
    // hardware round-robins that index over the 8 XCDs.
    const int wg  = blockIdx.y * 8 + blockIdx.x;  // 0..1023
    const int xcd = wg & 7;
    const int loc = wg >> 3;                      // 0..127
    const int bm0 = (xcd * 16 + (loc >> 3)) * 128;  // 16 M-tiles per XCD
    const int bn0 = (loc & 7) * 128;                // n fastest within stripe

    const int l15 = lane & 15, l4 = lane >> 4;

    const short* Ap = (const short*)Abf;
    const short* Bp = (const short*)Bsw;

    // staging: chunk c (0..511): row=c>>2 of A-tile, koff=(c&3)*8.
    // wave-instr j in {0,1}: c = (wave*2+j)*64 + lane; LDS linear at c*16B.
    const int c0 = (wave * 2 + 0) * 64 + lane;
    const int c1 = (wave * 2 + 1) * 64 + lane;
    const short* g0 = Ap + (size_t)(bm0 + (c0 >> 2)) * KK + (c0 & 3) * 8;
    const short* g1 = Ap + (size_t)(bm0 + (c1 >> 2)) * KK + (c1 & 3) * 8;

    int boff[4];
#pragma unroll
    for (int nt = 0; nt < 4; ++nt)
        boff[nt] = (((bn0 >> 4) + wn * 4 + nt) * 32) * 512 + lane * 8;

    int aoff[4];
#pragma unroll
    for (int mt = 0; mt < 4; ++mt)
        aoff[mt] = ((wm * 64 + mt * 16 + l15) * 4 + l4) * 8;

    floatx4 acc[4][4] = {};

    // ---- prologue: stage k-step 0 into buf 0, prefetch B[0] ----
    __builtin_amdgcn_global_load_lds(
        (const __attribute__((address_space(1))) unsigned int*)(g0),
        (__attribute__((address_space(3))) unsigned int*)&As[0][(wave * 2 + 0) * 512], 16, 0, 0);
    __builtin_amdgcn_global_load_lds(
        (const __attribute__((address_space(1))) unsigned int*)(g1),
        (__attribute__((address_space(3))) unsigned int*)&As[0][(wave * 2 + 1) * 512], 16, 0, 0);
    short8 bcur[4], bnxt[4];
#pragma unroll
    for (int nt = 0; nt < 4; ++nt)
        bcur[nt] = *(const short8*)(Bp + boff[nt]);
    __syncthreads();                              // buf0 staged, B[0] in regs

    for (int kb = 0; kb < 32; ++kb) {
        const int cur = kb & 1;
        const int nxt = cur ^ 1;
        if (kb < 31) {
            // issue next-tile staging + B prefetch BEFORE the MFMAs (T3)
            __builtin_amdgcn_global_load_lds(
                (const __attribute__((address_space(1))) unsigned int*)(g0 + (kb + 1) * 32),
                (__attribute__((address_space(3))) unsigned int*)&As[nxt][(wave * 2 + 0) * 512], 16, 0, 0);
            __builtin_amdgcn_global_load_lds(
                (const __attribute__((address_space(1))) unsigned int*)(g1 + (kb + 1) * 32),
                (__attribute__((address_space(3))) unsigned int*)&As[nxt][(wave * 2 + 1) * 512], 16, 0, 0);
#pragma unroll
            for (int nt = 0; nt < 4; ++nt)
                bnxt[nt] = *(const short8*)(Bp + boff[nt] + (kb + 1) * 512);
        }
        short8 a[4];
#pragma unroll
        for (int mt = 0; mt < 4; ++mt)
            a[mt] = *(const short8*)&As[cur][aoff[mt]];
#pragma unroll
        for (int mt = 0; mt < 4; ++mt)
#pragma unroll
            for (int nt = 0; nt < 4; ++nt)
                acc[mt][nt] = __builtin_amdgcn_mfma_f32_16x16x32_bf16(a[mt], bcur[nt], acc[mt][nt], 0, 0, 0);
        __syncthreads();                          // drains staging + B prefetch
#pragma unroll
        for (int nt = 0; nt < 4; ++nt)
            bcur[nt] = bnxt[nt];
    }

#pragma unroll
    for (int nt = 0; nt < 4; ++nt) {
        const int col = bn0 + wn * 64 + nt * 16 + l15;
        const float bv = bias[col];
#pragma unroll
        for (int mt = 0; mt < 4; ++mt) {
            const int row0 = bm0 + wm * 64 + mt * 16 + l4 * 4;
#pragma unroll
            for (int i = 0; i < 4; ++i)
                C[(size_t)(row0 + i) * NN + col] = acc[mt][nt][i] + bv;
        }
    }
}

// ---------------------------------------------------------------------------
extern "C" void kernel_launch(void* const* d_in, const int* in_sizes, int n_in,
                              void* d_out, int out_size, void* d_ws, size_t ws_size,
                              hipStream_t stream) {
    const float* x   = (const float*)d_in[0];
    const float* Kst = (const float*)d_in[1];
    const float* Vst = (const float*)d_in[2];
    const float* Wr  = (const float*)d_in[3];
    const float* Wo  = (const float*)d_in[4];
    const float* bo  = (const float*)d_in[5];
    const int*   kp  = (const int*)d_in[6];
    float* out = (float*)d_out;

    __hip_bfloat16* hb    = (__hip_bfloat16*)d_ws;             // 16M bf16 = 32 MiB
    __hip_bfloat16* wsw   = hb + (size_t)MM * KK;              // 1M bf16  = 2 MiB
    __hip_bfloat16* kfrag = wsw + (size_t)KK * NN;             // 256K bf16
    __hip_bfloat16* vfrag = kfrag + 16 * 32 * 512;             // 256K bf16

    convert_w<<<dim3(512), 256, 0, stream>>>(Wo, wsw);
    convert_kv<<<dim3(256), 256, 0, stream>>>(Kst, Vst, kfrag, vfrag);
    attn_v8b<<<dim3(NTOK / 64, HH), 512, 0, stream>>>(x, Wr, kfrag, vfrag, kp, hb);
    gemm_v3<<<dim3(NN / 128, MM / 128), 256, 0, stream>>>(hb, wsw, bo, out);
}

// Round 6
// 252.706 us; speedup vs baseline: 1.0179x; 1.0179x over previous
//
#include <hip/hip_runtime.h>
#include <hip/hip_bf16.h>

// Problem constants
#define BB 4
#define SS 4096
#define DM 1024
#define HH 16
#define PP 32
#define RR 8
#define DD 64
#define NTOK (BB*SS)          // 16384 tokens
#define MM NTOK               // GEMM M
#define NN DM                 // GEMM N
#define KK DM                 // GEMM K

typedef __attribute__((ext_vector_type(8))) short short8;
typedef __attribute__((ext_vector_type(4))) float floatx4;

static __device__ inline short f2bf(float f) {
    union { __hip_bfloat16 b; short s; } u; u.b = __float2bfloat16(f); return u.s;
}
static __device__ inline short8 pack8(float4 lo, float4 hi) {
    short8 r;
    r[0] = f2bf(lo.x); r[1] = f2bf(lo.y); r[2] = f2bf(lo.z); r[3] = f2bf(lo.w);
    r[4] = f2bf(hi.x); r[5] = f2bf(hi.y); r[6] = f2bf(hi.z); r[7] = f2bf(hi.w);
    return r;
}

// Fast RNE bf16 pack: identical bits to __float2bfloat16 for finite inputs.
static __device__ inline unsigned bfr(float f) {
    unsigned u = __float_as_uint(f);
    return u + 0x7fffu + ((u >> 16) & 1u);
}
static __device__ inline int pk2(float a, float b) {  // low16=bf(a), high16=bf(b)
    return __builtin_amdgcn_perm(bfr(b), bfr(a), 0x07060302);
}
static __device__ inline short8 pk8(float4 lo, float4 hi) {
    union { short8 s; int i[4]; } r;
    r.i[0] = pk2(lo.x, lo.y); r.i[1] = pk2(lo.z, lo.w);
    r.i[2] = pk2(hi.x, hi.y); r.i[3] = pk2(hi.z, hi.w);
    return r.s;
}

// ---------------------------------------------------------------------------
// Kernel 1: W_out (f32 [k][n]) -> bf16 MFMA B-fragment order (unchanged).
// ---------------------------------------------------------------------------
__global__ __launch_bounds__(256) void convert_w(const float* __restrict__ Wo,
                                                 __hip_bfloat16* __restrict__ wsw) {
    int tid = blockIdx.x * 256 + threadIdx.x;     // 0 .. 131071
    int l = tid & 63;
    int kblk = (tid >> 6) & 31;
    int ntile = tid >> 11;
    int col = ntile * 16 + (l & 15);
    int krow = kblk * 32 + (l >> 4) * 8;
#pragma unroll
    for (int j = 0; j < 8; ++j) {
        wsw[(size_t)tid * 8 + j] = __float2bfloat16(Wo[(size_t)(krow + j) * NN + col]);
    }
}

// ---------------------------------------------------------------------------
// Kernel 1b: K_state / V_state -> MFMA A-frag layouts (unchanged).
// ---------------------------------------------------------------------------
__global__ __launch_bounds__(256) void convert_kv(const float* __restrict__ Kst,
                                                  const float* __restrict__ Vst,
                                                  __hip_bfloat16* __restrict__ kfrag,
                                                  __hip_bfloat16* __restrict__ vfrag) {
    int tid = blockIdx.x * 256 + threadIdx.x;     // 0..65535
    int arr = tid >> 15;
    int idx = tid & 32767;
    int h = idx >> 11, blk = (idx >> 6) & 31, fl = idx & 63;
    int fm = fl & 15, fk = fl >> 4;
    short8 val;
    short* dst;
    if (arr == 0) {
        int mt = blk >> 1, kb = blk & 1;
        int pr = mt * 16 + fm, d0 = kb * 32 + fk * 8;
        const float* src = Kst + ((size_t)h * 256 + pr) * 64 + d0;
        float4 lo = *(const float4*)src, hi = *(const float4*)(src + 4);
        val = pack8(lo, hi);
        dst = (short*)kfrag + (size_t)idx * 8;
    } else {
        int mt = blk >> 3, kb = blk & 7;
        int d = mt * 16 + fm, pr0 = kb * 32 + fk * 8;
        const float* src = Vst + ((size_t)h * 256 + pr0) * 64 + d;
#pragma unroll
        for (int j = 0; j < 8; ++j) val[j] = f2bf(src[j * 64]);
        dst = (short*)vfrag + (size_t)idx * 8;
    }
    *(short8*)dst = val;
}

// ---------------------------------------------------------------------------
// Kernel 2 (v7, reverted): fused router + dense-MFMA SSE attention.
// R5 post-mortem: the 8-wave v8/v8b experiment regressed (105 -> 120 us):
// doubling waves doubled per-wave fixed overhead (wreg preload, xb operand
// duplication) and raised bank conflicts; occupancy gain (29->42%) did not
// pay. v7's 4-wave shape is the verified local optimum (105 us). Exact R3
// code, bit-identical output.
// ---------------------------------------------------------------------------
__global__ __launch_bounds__(256, 3) void attn_v7(const float* __restrict__ x,
                                                  const float* __restrict__ Wr,
                                                  const __hip_bfloat16* __restrict__ kfrag,
                                                  const __hip_bfloat16* __restrict__ vfrag,
                                                  const int* __restrict__ kp,
                                                  __hip_bfloat16* __restrict__ hb) {
    // Aliased LDS region (40960 B total = 160KiB/4):
    //   [0,32768):  wf (heads-phase B-frags)  -- written after top-k sync
    //   [0,17408):  xs[64][68]                -- dead after logits phase
    //   [17408,26624): Lg[64][36]             -- dead after top-k phase
    //   [32768,40960): gatesT[32][64]         -- live during wf phase (disjoint)
    __shared__ __align__(16) char smem[40960];
    float (*xs)[68]     = (float (*)[68])smem;
    float (*Lg)[36]     = (float (*)[36])(smem + 17408);
    short* wf           = (short*)smem;
    float (*gatesT)[64] = (float (*)[64])(smem + 32768);

    const int lane = threadIdx.x & 63;
    const int w = threadIdx.x >> 6;
    const int l15 = lane & 15, l4 = lane >> 4;
    const int t0 = blockIdx.x * 64;
    const int h = blockIdx.y;

    // ---- stage x tile [64 t x 64 d] into LDS ----
    {
        int row = threadIdx.x >> 2, q = threadIdx.x & 3;
        const float4* src = (const float4*)(x + (size_t)(t0 + row) * DM + h * 64 + q * 16);
        float4 v0 = src[0], v1 = src[1], v2 = src[2], v3 = src[3];
        float4* dst = (float4*)&xs[row][q * 16];
        dst[0] = v0; dst[1] = v1; dst[2] = v2; dst[3] = v3;
    }

    // ---- preload router weights (exact R1 pattern) ----
    const int p = lane & 31, dh = lane >> 5;
    float wreg[32];
    {
        const float* wrp = Wr + (size_t)h * (DD * PP) + dh * 32 * PP + p;
#pragma unroll
        for (int dd = 0; dd < 32; ++dd) wreg[dd] = wrp[dd * PP];
    }
    const int kkv = kp[0];

    // ---- scores GEMM operand loads: global only, no LDS dep -> pre-barrier
    short8 xb[4][2];
#pragma unroll
    for (int nt = 0; nt < 4; ++nt)
#pragma unroll
        for (int kb = 0; kb < 2; ++kb) {
            const float* bp = x + (size_t)(t0 + nt * 16 + l15) * DM + h * 64 + kb * 32 + l4 * 8;
            float4 lo = *(const float4*)bp;
            float4 hi = *(const float4*)(bp + 4);
            xb[nt][kb] = pk8(lo, hi);
        }
    short8 ka[4][2];
#pragma unroll
    for (int mi = 0; mi < 4; ++mi)
#pragma unroll
        for (int kb = 0; kb < 2; ++kb)
            ka[mi][kb] = *(const short8*)((const short*)kfrag +
                          ((size_t)(h * 32 + (w * 4 + mi) * 2 + kb) * 512 + lane * 8));

    __syncthreads();

    // ---- scores GEMM: S^T[pr][t] ----
    floatx4 acc[4][4] = {};
#pragma unroll
    for (int kb = 0; kb < 2; ++kb)
#pragma unroll
        for (int mi = 0; mi < 4; ++mi)
#pragma unroll
            for (int nt = 0; nt < 4; ++nt)
                acc[mi][nt] = __builtin_amdgcn_mfma_f32_16x16x32_bf16(ka[mi][kb], xb[nt][kb], acc[mi][nt], 0, 0, 0);

    // ---- logits: per-token chain order IDENTICAL to R1..R6; two tokens
    //      interleaved for ILP; direct float4 accumulate (no xf array) ----
    for (int it = 0; it < 16; it += 2) {
        const int ta = w * 16 + it;
        const int tb = ta + 1;
        float la = 0.f, lb = 0.f;
#pragma unroll
        for (int j = 0; j < 8; ++j) {
            float4 qa = *(const float4*)&xs[ta][dh * 32 + 4 * j];
            float4 qb = *(const float4*)&xs[tb][dh * 32 + 4 * j];
            la += qa.x * wreg[4 * j];     lb += qb.x * wreg[4 * j];
            la += qa.y * wreg[4 * j + 1]; lb += qb.y * wreg[4 * j + 1];
            la += qa.z * wreg[4 * j + 2]; lb += qb.z * wreg[4 * j + 2];
            la += qa.w * wreg[4 * j + 3]; lb += qb.w * wreg[4 * j + 3];
        }
        la += __shfl_xor(la, 32);
        lb += __shfl_xor(lb, 32);
        if (lane < 32) {
            Lg[ta][lane] = la;
            Lg[tb][lane] = lb;
        }
    }
    __syncthreads();

    // ---- top-k threshold: lanes 0..15, ladder bit-identical to R1..R6 ----
    float thresh = 0.f, a1 = 0.f;
    if (lane < 16) {
        int t = w * 16 + lane;
        float lgr[32];
        const float4* lrow = (const float4*)&Lg[t][0];
#pragma unroll
        for (int c = 0; c < 8; ++c) {
            float4 q4 = lrow[c];
            lgr[4 * c] = q4.x; lgr[4 * c + 1] = q4.y; lgr[4 * c + 2] = q4.z; lgr[4 * c + 3] = q4.w;
        }
        float aa = -INFINITY, b2 = -INFINITY, c3 = -INFINITY, d4 = -INFINITY;
#pragma unroll
        for (int pp = 0; pp < 32; ++pp) {
            float v = lgr[pp];
            float na = fmaxf(aa, v); v = fminf(aa, v); aa = na;
            float nb = fmaxf(b2, v); v = fminf(b2, v); b2 = nb;
            float nc = fmaxf(c3, v); v = fminf(c3, v); c3 = nc;
            d4 = fmaxf(d4, v);
        }
        thresh = (kkv >= 4) ? d4 : (kkv == 3 ? c3 : (kkv == 2 ? b2 : aa));
        a1 = aa;
    }
    // broadcast token-t threshold/max to the 3 sibling lanes (l4=1..3)
    thresh = __shfl(thresh, l15);
    a1     = __shfl(a1, l15);

    // ---- gates: all 64 lanes, 8 p-values each. exp/mask values identical
    //      bits to the serial version; only den's add order differs (smooth).
    {
        const int t = w * 16 + l15;
        const int p8 = l4 * 8;
        const float4* lrow = (const float4*)&Lg[t][p8];
        float4 qa = lrow[0], qb = lrow[1];
        float e0 = (qa.x >= thresh) ? __expf(qa.x - a1) : 0.f;
        float e1 = (qa.y >= thresh) ? __expf(qa.y - a1) : 0.f;
        float e2 = (qa.z >= thresh) ? __expf(qa.z - a1) : 0.f;
        float e3 = (qa.w >= thresh) ? __expf(qa.w - a1) : 0.f;
        float e4 = (qb.x >= thresh) ? __expf(qb.x - a1) : 0.f;
        float e5 = (qb.y >= thresh) ? __expf(qb.y - a1) : 0.f;
        float e6 = (qb.z >= thresh) ? __expf(qb.z - a1) : 0.f;
        float e7 = (qb.w >= thresh) ? __expf(qb.w - a1) : 0.f;
        float part = ((e0 + e1) + (e2 + e3)) + ((e4 + e5) + (e6 + e7));
        part += __shfl_xor(part, 16);
        part += __shfl_xor(part, 32);
        float inv = 1.f / part;
        gatesT[p8 + 0][t] = e0 * inv;
        gatesT[p8 + 1][t] = e1 * inv;
        gatesT[p8 + 2][t] = e2 * inv;
        gatesT[p8 + 3][t] = e3 * inv;
        gatesT[p8 + 4][t] = e4 * inv;
        gatesT[p8 + 5][t] = e5 * inv;
        gatesT[p8 + 6][t] = e6 * inv;
        gatesT[p8 + 7][t] = e7 * inv;
    }
    __syncthreads();

    // ---- r-softmax + gate -> w B-frags in LDS (overwrites dead xs/Lg) ----
#pragma unroll
    for (int mi = 0; mi < 4; ++mi) {
        const int mt = w * 4 + mi;
        const int pidx = mt * 2 + (l4 >> 1);
#pragma unroll
        for (int nt = 0; nt < 4; ++nt) {
            float g = gatesT[pidx][nt * 16 + l15];
            float s0 = acc[mi][nt][0] * 0.125f;
            float s1 = acc[mi][nt][1] * 0.125f;
            float s2 = acc[mi][nt][2] * 0.125f;
            float s3 = acc[mi][nt][3] * 0.125f;
            float mx = fmaxf(fmaxf(s0, s1), fmaxf(s2, s3));
            mx = fmaxf(mx, __shfl_xor(mx, 16));
            float e0 = __expf(s0 - mx), e1 = __expf(s1 - mx);
            float e2 = __expf(s2 - mx), e3 = __expf(s3 - mx);
            float loc = (e0 + e1) + (e2 + e3);
            float se = loc + __shfl_xor(loc, 16);
            float ws = g / se;
            int2 pk;
            pk.x = pk2(e0 * ws, e1 * ws);
            pk.y = pk2(e2 * ws, e3 * ws);
            int off = (((mt & 1) * 2 + (l4 >> 1)) * 16 + l15) * 8 + (l4 & 1) * 4;
            *(int2*)&wf[(nt * 8 + (mt >> 1)) * 512 + off] = pk;
        }
    }
    __syncthreads();

    // ---- heads GEMM: H^T[d][t] = Vfrag(A) @ wf(B) ----
    floatx4 h4[4] = {};
#pragma unroll
    for (int kb = 0; kb < 8; ++kb) {
        short8 va = *(const short8*)((const short*)vfrag +
                      ((size_t)(h * 32 + w * 8 + kb) * 512 + lane * 8));
#pragma unroll
        for (int nt = 0; nt < 4; ++nt) {
            short8 wb = *(const short8*)&wf[(nt * 8 + kb) * 512 + lane * 8];
            h4[nt] = __builtin_amdgcn_mfma_f32_16x16x32_bf16(va, wb, h4[nt], 0, 0, 0);
        }
    }
#pragma unroll
    for (int nt = 0; nt < 4; ++nt) {
        int t = t0 + nt * 16 + l15;
        int2 pk;
        pk.x = pk2(h4[nt][0], h4[nt][1]);
        pk.y = pk2(h4[nt][2], h4[nt][3]);
        *(int2*)((short*)hb + (size_t)t * DM + h * 64 + w * 16 + l4 * 4) = pk;
    }
}

// ---------------------------------------------------------------------------
// Kernel 3 (v4): BK=64 double-buffered GEMM — 32 MFMAs per barrier (was 16).
// Theory: each K-step's single barrier carries a full vmcnt(0) drain of the
// A-stage + B-prefetch (~300-500 cyc) amortized over only 16 MFMAs (~80 cyc).
// Halving the barrier count (32 -> 16 K-steps of 64) halves that overhead.
// Schedule per step: issue B(kbi=1) loads FIRST (so the compiler's wait for
// them before the kbi=1 MFMAs is a counted vmcnt over the younger A-stage,
// not a drain), then A-stage for step+1, then 16 MFMAs (kbi=0, operands
// prefetched last iter), 16 MFMAs (kbi=1), then B(kbi=0) prefetch for
// step+1, one barrier. MFMA accumulate order = kb 0..31 x (mt,nt), bit-
// identical to gemm_v3. B layout (wsw) and XCD stripe mapping unchanged.
// LDS 32 KB (2 x 128x64 bf16). Regs ~90 VGPR + 64 AGPR -> 3 waves/SIMD.
// ---------------------------------------------------------------------------
__global__ __launch_bounds__(256) void gemm_v4(const __hip_bfloat16* __restrict__ Abf,
                                               const __hip_bfloat16* __restrict__ Bsw,
                                               const float* __restrict__ bias,
                                               float* __restrict__ C) {
    __shared__ __align__(16) short As[2][8192];   // 2 x (128 rows x 64 k) = 32 KB
    const int lane = threadIdx.x & 63;
    const int wave = threadIdx.x >> 6;
    const int wm = wave >> 1, wn = wave & 1;

    // Bijective XCD-aware remap (nwg=1024, %8==0). Each XCD gets a 16-M-tile
    // stripe (4 MiB A panel = its L2), n fastest within the stripe.
    const int wg  = blockIdx.y * 8 + blockIdx.x;  // 0..1023
    const int xcd = wg & 7;
    const int loc = wg >> 3;                      // 0..127
    const int bm0 = (xcd * 16 + (loc >> 3)) * 128;
    const int bn0 = (loc & 7) * 128;

    const int l15 = lane & 15, l4 = lane >> 4;

    const short* Ap = (const short*)Abf;
    const short* Bp = (const short*)Bsw;

    // A staging, 128 rows x 64 k per step = 1024 chunks of 16B.
    // chunk c: row = c>>3, k8 = c&7 (k = k8*8). Wave instr j in 0..3:
    // c = (wave*4+j)*64 + lane; LDS linear at c*16B -> As row-major [128][64].
    int crow[4], ck8[4];
#pragma unroll
    for (int j = 0; j < 4; ++j) {
        int c = (wave * 4 + j) * 64 + lane;
        crow[j] = c >> 3; ck8[j] = (c & 7) * 8;
    }

    int boff[4];
#pragma unroll
    for (int nt = 0; nt < 4; ++nt)
        boff[nt] = (((bn0 >> 4) + wn * 4 + nt) * 32) * 512 + lane * 8;

    // a-frag read: As[row][k], row = wm*64+mt*16+l15, k = kbi*32 + l4*8
    int aoff[4];
#pragma unroll
    for (int mt = 0; mt < 4; ++mt)
        aoff[mt] = (wm * 64 + mt * 16 + l15) * 64 + l4 * 8;

    floatx4 acc[4][4] = {};

    // ---- prologue: stage step 0 into buf 0, prefetch B(step0, kbi0) ----
#pragma unroll
    for (int j = 0; j < 4; ++j)
        __builtin_amdgcn_global_load_lds(
            (const __attribute__((address_space(1))) unsigned int*)
                (Ap + (size_t)(bm0 + crow[j]) * KK + ck8[j]),
            (__attribute__((address_space(3))) unsigned int*)&As[0][(wave * 4 + j) * 512],
            16, 0, 0);
    short8 bA[4];
#pragma unroll
    for (int nt = 0; nt < 4; ++nt)
        bA[nt] = *(const short8*)(Bp + boff[nt]);
    __syncthreads();                              // buf0 staged, bA ready

    for (int step = 0; step < 16; ++step) {
        const int cur = step & 1;
        const int nxt = cur ^ 1;

        // B(step, kbi=1): issue FIRST so its wait is counted, not a drain.
        short8 bB[4];
#pragma unroll
        for (int nt = 0; nt < 4; ++nt)
            bB[nt] = *(const short8*)(Bp + boff[nt] + (size_t)(2 * step + 1) * 512);

        if (step < 15) {
            // stage step+1 into buf[nxt]
#pragma unroll
            for (int j = 0; j < 4; ++j)
                __builtin_amdgcn_global_load_lds(
                    (const __attribute__((address_space(1))) unsigned int*)
                        (Ap + (size_t)(bm0 + crow[j]) * KK + (step + 1) * 64 + ck8[j]),
                    (__attribute__((address_space(3))) unsigned int*)&As[nxt][(wave * 4 + j) * 512],
                    16, 0, 0);
        }

        // ---- kbi = 0 (kb = 2*step): operands bA prefetched last iter ----
        short8 a0[4];
#pragma unroll
        for (int mt = 0; mt < 4; ++mt)
            a0[mt] = *(const short8*)&As[cur][aoff[mt]];
#pragma unroll
        for (int mt = 0; mt < 4; ++mt)
#pragma unroll
            for (int nt = 0; nt < 4; ++nt)
                acc[mt][nt] = __builtin_amdgcn_mfma_f32_16x16x32_bf16(a0[mt], bA[nt], acc[mt][nt], 0, 0, 0);

        // ---- kbi = 1 (kb = 2*step+1): bB latency hidden by kbi=0 MFMAs ----
        short8 a1[4];
#pragma unroll
        for (int mt = 0; mt < 4; ++mt)
            a1[mt] = *(const short8*)&As[cur][aoff[mt] + 32];
#pragma unroll
        for (int mt = 0; mt < 4; ++mt)
#pragma unroll
            for (int nt = 0; nt < 4; ++nt)
                acc[mt][nt] = __builtin_amdgcn_mfma_f32_16x16x32_bf16(a1[mt], bB[nt], acc[mt][nt], 0, 0, 0);

        // B(step+1, kbi=0) prefetch; drained (with the stage) at the barrier.
        if (step < 15) {
#pragma unroll
            for (int nt = 0; nt < 4; ++nt)
                bA[nt] = *(const short8*)(Bp + boff[nt] + (size_t)(2 * step + 2) * 512);
        }
        __syncthreads();                          // buf[nxt] staged, bA ready
    }

#pragma unroll
    for (int nt = 0; nt < 4; ++nt) {
        const int col = bn0 + wn * 64 + nt * 16 + l15;
        const float bv = bias[col];
#pragma unroll
        for (int mt = 0; mt < 4; ++mt) {
            const int row0 = bm0 + wm * 64 + mt * 16 + l4 * 4;
#pragma unroll
            for (int i = 0; i < 4; ++i)
                C[(size_t)(row0 + i) * NN + col] = acc[mt][nt][i] + bv;
        }
    }
}

// ---------------------------------------------------------------------------
extern "C" void kernel_launch(void* const* d_in, const int* in_sizes, int n_in,
                              void* d_out, int out_size, void* d_ws, size_t ws_size,
                              hipStream_t stream) {
    const float* x   = (const float*)d_in[0];
    const float* Kst = (const float*)d_in[1];
    const float* Vst = (const float*)d_in[2];
    const float* Wr  = (const float*)d_in[3];
    const float* Wo  = (const float*)d_in[4];
    const float* bo  = (const float*)d_in[5];
    const int*   kp  = (const int*)d_in[6];
    float* out = (float*)d_out;

    __hip_bfloat16* hb    = (__hip_bfloat16*)d_ws;             // 16M bf16 = 32 MiB
    __hip_bfloat16* wsw   = hb + (size_t)MM * KK;              // 1M bf16  = 2 MiB
    __hip_bfloat16* kfrag = wsw + (size_t)KK * NN;             // 256K bf16
    __hip_bfloat16* vfrag = kfrag + 16 * 32 * 512;             // 256K bf16

    convert_w<<<dim3(512), 256, 0, stream>>>(Wo, wsw);
    convert_kv<<<dim3(256), 256, 0, stream>>>(Kst, Vst, kfrag, vfrag);
    attn_v7<<<dim3(NTOK / 64, HH), 256, 0, stream>>>(x, Wr, kfrag, vfrag, kp, hb);
    gemm_v4<<<dim3(NN / 128, MM / 128), 256, 0, stream>>>(hb, wsw, bo, out);
}

// Round 7
// 245.352 us; speedup vs baseline: 1.0484x; 1.0300x over previous
//
#include <hip/hip_runtime.h>
#include <hip/hip_bf16.h>

// Problem constants
#define BB 4
#define SS 4096
#define DM 1024
#define HH 16
#define PP 32
#define RR 8
#define DD 64
#define NTOK (BB*SS)          // 16384 tokens
#define MM NTOK               // GEMM M
#define NN DM                 // GEMM N
#define KK DM                 // GEMM K

typedef __attribute__((ext_vector_type(8))) short short8;
typedef __attribute__((ext_vector_type(4))) float floatx4;

static __device__ inline short f2bf(float f) {
    union { __hip_bfloat16 b; short s; } u; u.b = __float2bfloat16(f); return u.s;
}
static __device__ inline short8 pack8(float4 lo, float4 hi) {
    short8 r;
    r[0] = f2bf(lo.x); r[1] = f2bf(lo.y); r[2] = f2bf(lo.z); r[3] = f2bf(lo.w);
    r[4] = f2bf(hi.x); r[5] = f2bf(hi.y); r[6] = f2bf(hi.z); r[7] = f2bf(hi.w);
    return r;
}

// Fast RNE bf16 pack: identical bits to __float2bfloat16 for finite inputs.
static __device__ inline unsigned bfr(float f) {
    unsigned u = __float_as_uint(f);
    return u + 0x7fffu + ((u >> 16) & 1u);
}
static __device__ inline int pk2(float a, float b) {  // low16=bf(a), high16=bf(b)
    return __builtin_amdgcn_perm(bfr(b), bfr(a), 0x07060302);
}
static __device__ inline short8 pk8(float4 lo, float4 hi) {
    union { short8 s; int i[4]; } r;
    r.i[0] = pk2(lo.x, lo.y); r.i[1] = pk2(lo.z, lo.w);
    r.i[2] = pk2(hi.x, hi.y); r.i[3] = pk2(hi.z, hi.w);
    return r.s;
}

// ---------------------------------------------------------------------------
// Kernel 1: W_out (f32 [k][n]) -> bf16 MFMA B-fragment order (unchanged).
// ---------------------------------------------------------------------------
__global__ __launch_bounds__(256) void convert_w(const float* __restrict__ Wo,
                                                 __hip_bfloat16* __restrict__ wsw) {
    int tid = blockIdx.x * 256 + threadIdx.x;     // 0 .. 131071
    int l = tid & 63;
    int kblk = (tid >> 6) & 31;
    int ntile = tid >> 11;
    int col = ntile * 16 + (l & 15);
    int krow = kblk * 32 + (l >> 4) * 8;
#pragma unroll
    for (int j = 0; j < 8; ++j) {
        wsw[(size_t)tid * 8 + j] = __float2bfloat16(Wo[(size_t)(krow + j) * NN + col]);
    }
}

// ---------------------------------------------------------------------------
// Kernel 1b: K_state / V_state -> MFMA A-frag layouts (unchanged).
// ---------------------------------------------------------------------------
__global__ __launch_bounds__(256) void convert_kv(const float* __restrict__ Kst,
                                                  const float* __restrict__ Vst,
                                                  __hip_bfloat16* __restrict__ kfrag,
                                                  __hip_bfloat16* __restrict__ vfrag) {
    int tid = blockIdx.x * 256 + threadIdx.x;     // 0..65535
    int arr = tid >> 15;
    int idx = tid & 32767;
    int h = idx >> 11, blk = (idx >> 6) & 31, fl = idx & 63;
    int fm = fl & 15, fk = fl >> 4;
    short8 val;
    short* dst;
    if (arr == 0) {
        int mt = blk >> 1, kb = blk & 1;
        int pr = mt * 16 + fm, d0 = kb * 32 + fk * 8;
        const float* src = Kst + ((size_t)h * 256 + pr) * 64 + d0;
        float4 lo = *(const float4*)src, hi = *(const float4*)(src + 4);
        val = pack8(lo, hi);
        dst = (short*)kfrag + (size_t)idx * 8;
    } else {
        int mt = blk >> 3, kb = blk & 7;
        int d = mt * 16 + fm, pr0 = kb * 32 + fk * 8;
        const float* src = Vst + ((size_t)h * 256 + pr0) * 64 + d;
#pragma unroll
        for (int j = 0; j < 8; ++j) val[j] = f2bf(src[j * 64]);
        dst = (short*)vfrag + (size_t)idx * 8;
    }
    *(short8*)dst = val;
}

// ---------------------------------------------------------------------------
// Kernel 2 (v7): fused router + dense-MFMA SSE attention. Verified 105 us,
// occupancy register-capped (84 VGPR + 64 AGPR acc); 8-wave variant (R5)
// regressed. Unchanged from R6.
// ---------------------------------------------------------------------------
__global__ __launch_bounds__(256, 3) void attn_v7(const float* __restrict__ x,
                                                  const float* __restrict__ Wr,
                                                  const __hip_bfloat16* __restrict__ kfrag,
                                                  const __hip_bfloat16* __restrict__ vfrag,
                                                  const int* __restrict__ kp,
                                                  __hip_bfloat16* __restrict__ hb) {
    // Aliased LDS region (40960 B total = 160KiB/4):
    //   [0,32768):  wf (heads-phase B-frags)  -- written after top-k sync
    //   [0,17408):  xs[64][68]                -- dead after logits phase
    //   [17408,26624): Lg[64][36]             -- dead after top-k phase
    //   [32768,40960): gatesT[32][64]         -- live during wf phase (disjoint)
    __shared__ __align__(16) char smem[40960];
    float (*xs)[68]     = (float (*)[68])smem;
    float (*Lg)[36]     = (float (*)[36])(smem + 17408);
    short* wf           = (short*)smem;
    float (*gatesT)[64] = (float (*)[64])(smem + 32768);

    const int lane = threadIdx.x & 63;
    const int w = threadIdx.x >> 6;
    const int l15 = lane & 15, l4 = lane >> 4;
    const int t0 = blockIdx.x * 64;
    const int h = blockIdx.y;

    // ---- stage x tile [64 t x 64 d] into LDS ----
    {
        int row = threadIdx.x >> 2, q = threadIdx.x & 3;
        const float4* src = (const float4*)(x + (size_t)(t0 + row) * DM + h * 64 + q * 16);
        float4 v0 = src[0], v1 = src[1], v2 = src[2], v3 = src[3];
        float4* dst = (float4*)&xs[row][q * 16];
        dst[0] = v0; dst[1] = v1; dst[2] = v2; dst[3] = v3;
    }

    // ---- preload router weights (exact R1 pattern) ----
    const int p = lane & 31, dh = lane >> 5;
    float wreg[32];
    {
        const float* wrp = Wr + (size_t)h * (DD * PP) + dh * 32 * PP + p;
#pragma unroll
        for (int dd = 0; dd < 32; ++dd) wreg[dd] = wrp[dd * PP];
    }
    const int kkv = kp[0];

    // ---- scores GEMM operand loads: global only, no LDS dep -> pre-barrier
    short8 xb[4][2];
#pragma unroll
    for (int nt = 0; nt < 4; ++nt)
#pragma unroll
        for (int kb = 0; kb < 2; ++kb) {
            const float* bp = x + (size_t)(t0 + nt * 16 + l15) * DM + h * 64 + kb * 32 + l4 * 8;
            float4 lo = *(const float4*)bp;
            float4 hi = *(const float4*)(bp + 4);
            xb[nt][kb] = pk8(lo, hi);
        }
    short8 ka[4][2];
#pragma unroll
    for (int mi = 0; mi < 4; ++mi)
#pragma unroll
        for (int kb = 0; kb < 2; ++kb)
            ka[mi][kb] = *(const short8*)((const short*)kfrag +
                          ((size_t)(h * 32 + (w * 4 + mi) * 2 + kb) * 512 + lane * 8));

    __syncthreads();

    // ---- scores GEMM: S^T[pr][t] ----
    floatx4 acc[4][4] = {};
#pragma unroll
    for (int kb = 0; kb < 2; ++kb)
#pragma unroll
        for (int mi = 0; mi < 4; ++mi)
#pragma unroll
            for (int nt = 0; nt < 4; ++nt)
                acc[mi][nt] = __builtin_amdgcn_mfma_f32_16x16x32_bf16(ka[mi][kb], xb[nt][kb], acc[mi][nt], 0, 0, 0);

    // ---- logits: per-token chain order IDENTICAL to R1..R6; two tokens
    //      interleaved for ILP; direct float4 accumulate (no xf array) ----
    for (int it = 0; it < 16; it += 2) {
        const int ta = w * 16 + it;
        const int tb = ta + 1;
        float la = 0.f, lb = 0.f;
#pragma unroll
        for (int j = 0; j < 8; ++j) {
            float4 qa = *(const float4*)&xs[ta][dh * 32 + 4 * j];
            float4 qb = *(const float4*)&xs[tb][dh * 32 + 4 * j];
            la += qa.x * wreg[4 * j];     lb += qb.x * wreg[4 * j];
            la += qa.y * wreg[4 * j + 1]; lb += qb.y * wreg[4 * j + 1];
            la += qa.z * wreg[4 * j + 2]; lb += qb.z * wreg[4 * j + 2];
            la += qa.w * wreg[4 * j + 3]; lb += qb.w * wreg[4 * j + 3];
        }
        la += __shfl_xor(la, 32);
        lb += __shfl_xor(lb, 32);
        if (lane < 32) {
            Lg[ta][lane] = la;
            Lg[tb][lane] = lb;
        }
    }
    __syncthreads();

    // ---- top-k threshold: lanes 0..15, ladder bit-identical to R1..R6 ----
    float thresh = 0.f, a1 = 0.f;
    if (lane < 16) {
        int t = w * 16 + lane;
        float lgr[32];
        const float4* lrow = (const float4*)&Lg[t][0];
#pragma unroll
        for (int c = 0; c < 8; ++c) {
            float4 q4 = lrow[c];
            lgr[4 * c] = q4.x; lgr[4 * c + 1] = q4.y; lgr[4 * c + 2] = q4.z; lgr[4 * c + 3] = q4.w;
        }
        float aa = -INFINITY, b2 = -INFINITY, c3 = -INFINITY, d4 = -INFINITY;
#pragma unroll
        for (int pp = 0; pp < 32; ++pp) {
            float v = lgr[pp];
            float na = fmaxf(aa, v); v = fminf(aa, v); aa = na;
            float nb = fmaxf(b2, v); v = fminf(b2, v); b2 = nb;
            float nc = fmaxf(c3, v); v = fminf(c3, v); c3 = nc;
            d4 = fmaxf(d4, v);
        }
        thresh = (kkv >= 4) ? d4 : (kkv == 3 ? c3 : (kkv == 2 ? b2 : aa));
        a1 = aa;
    }
    // broadcast token-t threshold/max to the 3 sibling lanes (l4=1..3)
    thresh = __shfl(thresh, l15);
    a1     = __shfl(a1, l15);

    // ---- gates: all 64 lanes, 8 p-values each. exp/mask values identical
    //      bits to the serial version; only den's add order differs (smooth).
    {
        const int t = w * 16 + l15;
        const int p8 = l4 * 8;
        const float4* lrow = (const float4*)&Lg[t][p8];
        float4 qa = lrow[0], qb = lrow[1];
        float e0 = (qa.x >= thresh) ? __expf(qa.x - a1) : 0.f;
        float e1 = (qa.y >= thresh) ? __expf(qa.y - a1) : 0.f;
        float e2 = (qa.z >= thresh) ? __expf(qa.z - a1) : 0.f;
        float e3 = (qa.w >= thresh) ? __expf(qa.w - a1) : 0.f;
        float e4 = (qb.x >= thresh) ? __expf(qb.x - a1) : 0.f;
        float e5 = (qb.y >= thresh) ? __expf(qb.y - a1) : 0.f;
        float e6 = (qb.z >= thresh) ? __expf(qb.z - a1) : 0.f;
        float e7 = (qb.w >= thresh) ? __expf(qb.w - a1) : 0.f;
        float part = ((e0 + e1) + (e2 + e3)) + ((e4 + e5) + (e6 + e7));
        part += __shfl_xor(part, 16);
        part += __shfl_xor(part, 32);
        float inv = 1.f / part;
        gatesT[p8 + 0][t] = e0 * inv;
        gatesT[p8 + 1][t] = e1 * inv;
        gatesT[p8 + 2][t] = e2 * inv;
        gatesT[p8 + 3][t] = e3 * inv;
        gatesT[p8 + 4][t] = e4 * inv;
        gatesT[p8 + 5][t] = e5 * inv;
        gatesT[p8 + 6][t] = e6 * inv;
        gatesT[p8 + 7][t] = e7 * inv;
    }
    __syncthreads();

    // ---- r-softmax + gate -> w B-frags in LDS (overwrites dead xs/Lg) ----
#pragma unroll
    for (int mi = 0; mi < 4; ++mi) {
        const int mt = w * 4 + mi;
        const int pidx = mt * 2 + (l4 >> 1);
#pragma unroll
        for (int nt = 0; nt < 4; ++nt) {
            float g = gatesT[pidx][nt * 16 + l15];
            float s0 = acc[mi][nt][0] * 0.125f;
            float s1 = acc[mi][nt][1] * 0.125f;
            float s2 = acc[mi][nt][2] * 0.125f;
            float s3 = acc[mi][nt][3] * 0.125f;
            float mx = fmaxf(fmaxf(s0, s1), fmaxf(s2, s3));
            mx = fmaxf(mx, __shfl_xor(mx, 16));
            float e0 = __expf(s0 - mx), e1 = __expf(s1 - mx);
            float e2 = __expf(s2 - mx), e3 = __expf(s3 - mx);
            float loc = (e0 + e1) + (e2 + e3);
            float se = loc + __shfl_xor(loc, 16);
            float ws = g / se;
            int2 pk;
            pk.x = pk2(e0 * ws, e1 * ws);
            pk.y = pk2(e2 * ws, e3 * ws);
            int off = (((mt & 1) * 2 + (l4 >> 1)) * 16 + l15) * 8 + (l4 & 1) * 4;
            *(int2*)&wf[(nt * 8 + (mt >> 1)) * 512 + off] = pk;
        }
    }
    __syncthreads();

    // ---- heads GEMM: H^T[d][t] = Vfrag(A) @ wf(B) ----
    floatx4 h4[4] = {};
#pragma unroll
    for (int kb = 0; kb < 8; ++kb) {
        short8 va = *(const short8*)((const short*)vfrag +
                      ((size_t)(h * 32 + w * 8 + kb) * 512 + lane * 8));
#pragma unroll
        for (int nt = 0; nt < 4; ++nt) {
            short8 wb = *(const short8*)&wf[(nt * 8 + kb) * 512 + lane * 8];
            h4[nt] = __builtin_amdgcn_mfma_f32_16x16x32_bf16(va, wb, h4[nt], 0, 0, 0);
        }
    }
#pragma unroll
    for (int nt = 0; nt < 4; ++nt) {
        int t = t0 + nt * 16 + l15;
        int2 pk;
        pk.x = pk2(h4[nt][0], h4[nt][1]);
        pk.y = pk2(h4[nt][2], h4[nt][3]);
        *(int2*)((short*)hb + (size_t)t * DM + h * 64 + w * 16 + l4 * 4) = pk;
    }
}

// ---------------------------------------------------------------------------
// Kernel 3 (v5): gemm_v4 + T2 XOR-swizzle on the A LDS tile.
// R6 post-mortem: halving barriers (v4) was neutral -> gemm is not
// barrier-drain-bound. Bank arithmetic: v4's [128][64] layout puts the
// A-frag ds_read_b128 of lanes 0-15 (rows 0..15, same k) ALL on one bank
// (row*128 B / 4 % 32 == const) = 16-way conflict (5.69x, m136); v3's
// layout was 8-way. Fix per T2 / G4: physical k8 = logical k8 ^ (row&7).
// Applied BOTH sides (rule #21): inverse XOR on the per-lane GLOBAL source
// address of global_load_lds (LDS dest stays linear), same XOR on ds_read
// addr. Involution; staging stays coalesced (8 lanes permute within their
// own 128 B row segment). Read banks: lanes 0-15 spread over 8 bank-groups,
// 2-way = free. Pure layout change -> bit-identical output to v3/v4.
// ---------------------------------------------------------------------------
__global__ __launch_bounds__(256) void gemm_v5(const __hip_bfloat16* __restrict__ Abf,
                                               const __hip_bfloat16* __restrict__ Bsw,
                                               const float* __restrict__ bias,
                                               float* __restrict__ C) {
    __shared__ __align__(16) short As[2][8192];   // 2 x [128 rows][64 k] bf16, swizzled
    const int lane = threadIdx.x & 63;
    const int wave = threadIdx.x >> 6;
    const int wm = wave >> 1, wn = wave & 1;

    // Bijective XCD-aware remap (nwg=1024, %8==0). Each XCD gets a 16-M-tile
    // stripe (4 MiB A panel = its L2), n fastest within the stripe.
    const int wg  = blockIdx.y * 8 + blockIdx.x;  // 0..1023
    const int xcd = wg & 7;
    const int loc = wg >> 3;                      // 0..127
    const int bm0 = (xcd * 16 + (loc >> 3)) * 128;
    const int bn0 = (loc & 7) * 128;

    const int l15 = lane & 15, l4 = lane >> 4;

    const short* Ap = (const short*)Abf;
    const short* Bp = (const short*)Bsw;

    // A staging with swizzle: LDS chunk c (16 B) = logical (row = c>>3,
    // k8 = (c&7) ^ (row&7)). Inverse XOR on the global source; LDS linear.
    int crow[4], ck8[4];
#pragma unroll
    for (int j = 0; j < 4; ++j) {
        int c = (wave * 4 + j) * 64 + lane;
        int row = c >> 3;
        crow[j] = row;
        ck8[j] = ((c & 7) ^ (row & 7)) * 8;
    }

    int boff[4];
#pragma unroll
    for (int nt = 0; nt < 4; ++nt)
        boff[nt] = (((bn0 >> 4) + wn * 4 + nt) * 32) * 512 + lane * 8;

    // A-frag read (shorts): row*64 + ((kbi*4 + l4) ^ (row&7)) * 8,
    // row = wm*64 + mt*16 + l15 (row&7 == l15&7).
    const int axor = l15 & 7;
    int arow[4];
#pragma unroll
    for (int mt = 0; mt < 4; ++mt)
        arow[mt] = (wm * 64 + mt * 16 + l15) * 64;
    const int ak0 = (l4 ^ axor) * 8;              // kbi = 0 (k = l4*8)
    const int ak1 = ((4 + l4) ^ axor) * 8;        // kbi = 1 (k = 32 + l4*8)

    floatx4 acc[4][4] = {};

    // ---- prologue: stage step 0 into buf 0, prefetch B(step0, kbi0) ----
#pragma unroll
    for (int j = 0; j < 4; ++j)
        __builtin_amdgcn_global_load_lds(
            (const __attribute__((address_space(1))) unsigned int*)
                (Ap + (size_t)(bm0 + crow[j]) * KK + ck8[j]),
            (__attribute__((address_space(3))) unsigned int*)&As[0][(wave * 4 + j) * 512],
            16, 0, 0);
    short8 bA[4];
#pragma unroll
    for (int nt = 0; nt < 4; ++nt)
        bA[nt] = *(const short8*)(Bp + boff[nt]);
    __syncthreads();                              // buf0 staged, bA ready

    for (int step = 0; step < 16; ++step) {
        const int cur = step & 1;
        const int nxt = cur ^ 1;

        // B(step, kbi=1): issue FIRST so its wait is counted, not a drain.
        short8 bB[4];
#pragma unroll
        for (int nt = 0; nt < 4; ++nt)
            bB[nt] = *(const short8*)(Bp + boff[nt] + (size_t)(2 * step + 1) * 512);

        if (step < 15) {
            // stage step+1 into buf[nxt]
#pragma unroll
            for (int j = 0; j < 4; ++j)
                __builtin_amdgcn_global_load_lds(
                    (const __attribute__((address_space(1))) unsigned int*)
                        (Ap + (size_t)(bm0 + crow[j]) * KK + (step + 1) * 64 + ck8[j]),
                    (__attribute__((address_space(3))) unsigned int*)&As[nxt][(wave * 4 + j) * 512],
                    16, 0, 0);
        }

        // ---- kbi = 0 (kb = 2*step): operands bA prefetched last iter ----
        short8 a0[4];
#pragma unroll
        for (int mt = 0; mt < 4; ++mt)
            a0[mt] = *(const short8*)&As[cur][arow[mt] + ak0];
#pragma unroll
        for (int mt = 0; mt < 4; ++mt)
#pragma unroll
            for (int nt = 0; nt < 4; ++nt)
                acc[mt][nt] = __builtin_amdgcn_mfma_f32_16x16x32_bf16(a0[mt], bA[nt], acc[mt][nt], 0, 0, 0);

        // ---- kbi = 1 (kb = 2*step+1): bB latency hidden by kbi=0 MFMAs ----
        short8 a1[4];
#pragma unroll
        for (int mt = 0; mt < 4; ++mt)
            a1[mt] = *(const short8*)&As[cur][arow[mt] + ak1];
#pragma unroll
        for (int mt = 0; mt < 4; ++mt)
#pragma unroll
            for (int nt = 0; nt < 4; ++nt)
                acc[mt][nt] = __builtin_amdgcn_mfma_f32_16x16x32_bf16(a1[mt], bB[nt], acc[mt][nt], 0, 0, 0);

        // B(step+1, kbi=0) prefetch; drained (with the stage) at the barrier.
        if (step < 15) {
#pragma unroll
            for (int nt = 0; nt < 4; ++nt)
                bA[nt] = *(const short8*)(Bp + boff[nt] + (size_t)(2 * step + 2) * 512);
        }
        __syncthreads();                          // buf[nxt] staged, bA ready
    }

#pragma unroll
    for (int nt = 0; nt < 4; ++nt) {
        const int col = bn0 + wn * 64 + nt * 16 + l15;
        const float bv = bias[col];
#pragma unroll
        for (int mt = 0; mt < 4; ++mt) {
            const int row0 = bm0 + wm * 64 + mt * 16 + l4 * 4;
#pragma unroll
            for (int i = 0; i < 4; ++i)
                C[(size_t)(row0 + i) * NN + col] = acc[mt][nt][i] + bv;
        }
    }
}

// ---------------------------------------------------------------------------
extern "C" void kernel_launch(void* const* d_in, const int* in_sizes, int n_in,
                              void* d_out, int out_size, void* d_ws, size_t ws_size,
                              hipStream_t stream) {
    const float* x   = (const float*)d_in[0];
    const float* Kst = (const float*)d_in[1];
    const float* Vst = (const float*)d_in[2];
    const float* Wr  = (const float*)d_in[3];
    const float* Wo  = (const float*)d_in[4];
    const float* bo  = (const float*)d_in[5];
    const int*   kp  = (const int*)d_in[6];
    float* out = (float*)d_out;

    __hip_bfloat16* hb    = (__hip_bfloat16*)d_ws;             // 16M bf16 = 32 MiB
    __hip_bfloat16* wsw   = hb + (size_t)MM * KK;              // 1M bf16  = 2 MiB
    __hip_bfloat16* kfrag = wsw + (size_t)KK * NN;             // 256K bf16
    __hip_bfloat16* vfrag = kfrag + 16 * 32 * 512;             // 256K bf16

    convert_w<<<dim3(512), 256, 0, stream>>>(Wo, wsw);
    convert_kv<<<dim3(256), 256, 0, stream>>>(Kst, Vst, kfrag, vfrag);
    attn_v7<<<dim3(NTOK / 64, HH), 256, 0, stream>>>(x, Wr, kfrag, vfrag, kp, hb);
    gemm_v5<<<dim3(NN / 128, MM / 128), 256, 0, stream>>>(hb, wsw, bo, out);
}